// Round 14
// baseline (513.795 us; speedup 1.0000x reference)
//
#include <hip/hip_runtime.h>
#include <cstdint>
#include <cstddef>

#define SLOPE 0.2f
#define HEADS 8

typedef __bf16 bf16_t;
typedef __bf16 bf16x8 __attribute__((ext_vector_type(8)));
typedef float f32x4 __attribute__((ext_vector_type(4)));

// ---- weight prep: W1t/W2t transpose to bf16 + Wel2/Wer2 projection rows ----
__global__ void prep_weights(const float* __restrict__ W1, const float* __restrict__ W2,
                             const float* __restrict__ al2, const float* __restrict__ ar2,
                             bf16_t* __restrict__ W1t, bf16_t* __restrict__ W2t) {
  int gid = blockIdx.x * blockDim.x + threadIdx.x;
  if (gid < 512 * 512) {
    int nn = gid >> 9, kk = gid & 511;
    W1t[gid] = (bf16_t)W1[(size_t)kk * 512 + nn];
  } else if (gid < 512 * 512 + 320 * 512) {
    int g = gid - 512 * 512;
    int nn = g >> 9, kk = g & 511;
    W2t[g] = (bf16_t)W2[(size_t)kk * 320 + nn];
  } else if (gid < 512 * 512 + 320 * 512 + 8 * 512) {
    int g = gid - (512 * 512 + 320 * 512);
    int h = g >> 9, k = g & 511;
    float a = 0.f, b = 0.f;
    for (int d = 0; d < 40; ++d) {
      float w = W2[(size_t)k * 320 + h * 40 + d];
      a = fmaf(w, al2[h * 40 + d], a);
      b = fmaf(w, ar2[h * 40 + d], b);
    }
    W2t[(size_t)(320 + h) * 512 + k] = (bf16_t)a;
    W2t[(size_t)(328 + h) * 512 + k] = (bf16_t)b;
  }
}

// ---------------- layer-1 GEMM: Cb[M,512] = bf16(A_f32[M,K]) * Bt[512,K]^T ----------------
// A loaded fp32 via global_load_lds into 32KB LDS (16B-granule XOR swizzle: physical slot p
// holds logical p ^ ((row&7)<<4) — fixed from r9's 32B-granule 4-way-conflict bug); cvt
// fp32->bf16 at LDS->reg read. B path = proven bf16 path. el1/er1 fused in epilogue:
// wave's 64-col span == one head; 4-FMA + 16-lane shfl reduce from fp32 acc.
__global__ __launch_bounds__(256) void gemm_af32(
    const float* __restrict__ A,    // [M][K] fp32 (unpadded; OOB rows clamped)
    const bf16_t* __restrict__ Bt,  // [512][K] bf16
    bf16_t* __restrict__ Cb,        // [M][512] bf16
    const float* __restrict__ al, const float* __restrict__ ar,
    float* __restrict__ elp, float* __restrict__ erp,
    int M, int Nc, int K) {
  __shared__ __align__(16) unsigned char lds[49152];  // A fp32: [0,32K), B bf16: [32K,48K)
  const int tid = threadIdx.x;
  const int wid = tid >> 6, lane = tid & 63;
  const int wm = wid >> 1, wn = wid & 1;
  const int bm = blockIdx.y * 128, bn = blockIdx.x * 128;  // col tiles fastest
  const int quad = lane >> 4, lrow = lane & 15;

  f32x4 acc[4][4] = {};

  // A staging: chunk (i,wid) covers rows [16i+4wid, +4), 1KB per glds call.
  // lane l -> row 16i+4wid+(l>>4), physical slot (l&15)*16B; source col pre-swizzled
  // at 16B granule: fp32 col = ((l&15)*4) ^ ((row&7)<<2), row&7 = 4*(wid&1)+(l>>4).
  const int arow_in = 4 * wid + (lane >> 4);
  const int acol_src = ((lane & 15) * 4) ^ ((4 * (wid & 1) + (lane >> 4)) << 2);  // fp32 units
  // B staging (proven geometry, 16B granule XOR)
  const int st_sub = wid * 8 + (lane >> 3);
  const int st_k = 8 * ((lane & 7) ^ (lane >> 3));
  const bf16_t* bSrc = Bt + (size_t)(bn + st_sub) * K + st_k;

  const int x16 = (lrow & 7) << 4;
  const int aRdRow = (wm * 64 + lrow) * 256;           // + mf*4096 + swizzled slot
  const int bRdBase = (wn * 64 + lrow) * 128 + 32768;  // + nf*2048 + kb

  for (int k0 = 0; k0 < K; k0 += 64) {
    if (k0) __syncthreads();
#pragma unroll
    for (int i = 0; i < 8; ++i) {
      int rg = bm + 16 * i + arow_in;
      rg = rg < M ? rg : M - 1;  // clamp; clamped rows' outputs never stored
      __builtin_amdgcn_global_load_lds(
          (const __attribute__((address_space(1))) void*)(A + (size_t)rg * K + k0 + acol_src),
          (__attribute__((address_space(3))) void*)(lds + (i * 4 + wid) * 1024), 16, 0, 0);
    }
#pragma unroll
    for (int i = 0; i < 4; ++i) {
      __builtin_amdgcn_global_load_lds(
          (const __attribute__((address_space(1))) void*)(bSrc + (size_t)i * 32 * K + k0),
          (__attribute__((address_space(3))) void*)(lds + 32768 + (i * 4 + wid) * 1024), 16, 0, 0);
    }
    __syncthreads();
#pragma unroll
    for (int kk = 0; kk < 2; ++kk) {
      bf16x8 af[4], bfr[4];
      const int slotB = kk * 128 + quad * 32;          // logical 32B A-slot (fp32 k-range)
      const int kb = (kk * 64 + quad * 16) ^ x16;      // B slot (bf16)
#pragma unroll
      for (int mf = 0; mf < 4; ++mf) {
        f32x4 lo = *(const f32x4*)(lds + aRdRow + mf * 4096 + (slotB ^ x16));
        f32x4 hi = *(const f32x4*)(lds + aRdRow + mf * 4096 + ((slotB + 16) ^ x16));
        bf16x8 t;
        t[0] = (bf16_t)lo[0]; t[1] = (bf16_t)lo[1]; t[2] = (bf16_t)lo[2]; t[3] = (bf16_t)lo[3];
        t[4] = (bf16_t)hi[0]; t[5] = (bf16_t)hi[1]; t[6] = (bf16_t)hi[2]; t[7] = (bf16_t)hi[3];
        af[mf] = t;
      }
#pragma unroll
      for (int nf = 0; nf < 4; ++nf)
        bfr[nf] = *(const bf16x8*)(lds + bRdBase + nf * 2048 + kb);
#pragma unroll
      for (int mf = 0; mf < 4; ++mf)
#pragma unroll
        for (int nf = 0; nf < 4; ++nf)
          acc[mf][nf] =
              __builtin_amdgcn_mfma_f32_16x16x32_bf16(af[mf], bfr[nf], acc[mf][nf], 0, 0, 0);
    }
  }

  // C/D layout (verified m89/m91): col = lane&15, row = (lane>>4)*4 + reg
  const int crow0 = bm + wm * 64 + quad * 4;
  const int ccol0 = bn + wn * 64 + lrow;
#pragma unroll
  for (int mf = 0; mf < 4; ++mf) {
#pragma unroll
    for (int r2 = 0; r2 < 4; ++r2) {
      int row = crow0 + mf * 16 + r2;
      if (row < M) {
#pragma unroll
        for (int nf = 0; nf < 4; ++nf) {
          int col = ccol0 + nf * 16;
          if (col < Nc) Cb[(size_t)row * Nc + col] = (bf16_t)acc[mf][nf][r2];
        }
      }
    }
  }

  // fused el1/er1: this wave's 64-col span == head hh
  {
    const int hh = (bn >> 6) + wn;
    float alv[4], arv[4];
#pragma unroll
    for (int nf = 0; nf < 4; ++nf) {
      alv[nf] = al[hh * 64 + lrow + nf * 16];
      arv[nf] = ar[hh * 64 + lrow + nf * 16];
    }
#pragma unroll
    for (int mf = 0; mf < 4; ++mf) {
#pragma unroll
      for (int r2 = 0; r2 < 4; ++r2) {
        float pe = 0.f, pr = 0.f;
#pragma unroll
        for (int nf = 0; nf < 4; ++nf) {
          float v = acc[mf][nf][r2];
          pe = fmaf(v, alv[nf], pe);
          pr = fmaf(v, arv[nf], pr);
        }
#pragma unroll
        for (int mask = 1; mask < 16; mask <<= 1) {
          pe += __shfl_xor(pe, mask, 64);
          pr += __shfl_xor(pr, mask, 64);
        }
        int row = crow0 + mf * 16 + r2;
        if (lrow == 0 && row < M) {
          elp[(size_t)row * 8 + hh] = pe;
          erp[(size_t)row * 8 + hh] = pr;
        }
      }
    }
  }
}

// ---------------- layer-2 GEMM (bf16 A via glds) + fused el/er epilogue ----------------
__global__ __launch_bounds__(256) void gemm_bf16_l2(
    const bf16_t* __restrict__ A,   // [Mp][K] bf16 (pad rows zeroed)
    const bf16_t* __restrict__ Bt,  // [384][K] bf16 (rows [336,384) zeroed)
    bf16_t* __restrict__ Cb,        // [M][320] bf16
    float* __restrict__ elp, float* __restrict__ erp,
    int M, int NcFeat, int K) {
  __shared__ __align__(16) unsigned char lds[32768];  // A: [0,16K), B: [16K,32K)
  const int tid = threadIdx.x;
  const int wid = tid >> 6, lane = tid & 63;
  const int wm = wid >> 1, wn = wid & 1;
  const int bm = blockIdx.y * 128, bn = blockIdx.x * 128;  // col tiles fastest
  const int quad = lane >> 4, lrow = lane & 15;

  f32x4 acc[4][4] = {};

  const int st_sub = wid * 8 + (lane >> 3);
  const int st_k = 8 * ((lane & 7) ^ (lane >> 3));
  const bf16_t* aSrc = A + (size_t)(bm + st_sub) * K + st_k;
  const bf16_t* bSrc = Bt + (size_t)(bn + st_sub) * K + st_k;

  const int xorv = (lrow & 7) << 4;
  const int aRdBase = (wm * 64 + lrow) * 128;
  const int bRdBase = (wn * 64 + lrow) * 128 + 16384;

  for (int k0 = 0; k0 < K; k0 += 64) {
    if (k0) __syncthreads();
#pragma unroll
    for (int i = 0; i < 4; ++i) {
      __builtin_amdgcn_global_load_lds(
          (const __attribute__((address_space(1))) void*)(aSrc + (size_t)i * 32 * K + k0),
          (__attribute__((address_space(3))) void*)(lds + (i * 4 + wid) * 1024), 16, 0, 0);
    }
#pragma unroll
    for (int i = 0; i < 4; ++i) {
      __builtin_amdgcn_global_load_lds(
          (const __attribute__((address_space(1))) void*)(bSrc + (size_t)i * 32 * K + k0),
          (__attribute__((address_space(3))) void*)(lds + 16384 + (i * 4 + wid) * 1024), 16, 0, 0);
    }
    __syncthreads();
#pragma unroll
    for (int kk = 0; kk < 2; ++kk) {
      bf16x8 af[4], bfr[4];
      const int kb = (kk * 64 + quad * 16) ^ xorv;
#pragma unroll
      for (int mf = 0; mf < 4; ++mf)
        af[mf] = *(const bf16x8*)(lds + aRdBase + mf * 2048 + kb);
#pragma unroll
      for (int nf = 0; nf < 4; ++nf)
        bfr[nf] = *(const bf16x8*)(lds + bRdBase + nf * 2048 + kb);
#pragma unroll
      for (int mf = 0; mf < 4; ++mf)
#pragma unroll
        for (int nf = 0; nf < 4; ++nf)
          acc[mf][nf] =
              __builtin_amdgcn_mfma_f32_16x16x32_bf16(af[mf], bfr[nf], acc[mf][nf], 0, 0, 0);
    }
  }

  const int crow0 = bm + wm * 64 + quad * 4;
  const int ccol0 = bn + wn * 64 + lrow;
#pragma unroll
  for (int mf = 0; mf < 4; ++mf) {
#pragma unroll
    for (int r2 = 0; r2 < 4; ++r2) {
      int row = crow0 + mf * 16 + r2;
      if (row < M) {
#pragma unroll
        for (int nf = 0; nf < 4; ++nf) {
          int col = ccol0 + nf * 16;
          float v = acc[mf][nf][r2];
          if (col < NcFeat) {
            Cb[(size_t)row * NcFeat + col] = (bf16_t)v;
          } else if (col < NcFeat + 8) {
            elp[(size_t)row * 8 + (col - NcFeat)] = v;
          } else if (col < NcFeat + 16) {
            erp[(size_t)row * 8 + (col - NcFeat - 8)] = v;
          }
        }
      }
    }
  }
}

// ---------------- CSR build ----------------
__global__ void count_deg(const int* __restrict__ dst, int* __restrict__ deg, int e) {
  int gid = blockIdx.x * blockDim.x + threadIdx.x;
  if (gid < e) atomicAdd(&deg[dst[gid]], 1);
}

__global__ void scan_block(const int* __restrict__ deg, int* __restrict__ incl,
                           int* __restrict__ bsum, int n) {
  __shared__ int tmp[256];
  int t = threadIdx.x;
  int gid = blockIdx.x * 256 + t;
  int v = (gid < n) ? deg[gid] : 0;
  tmp[t] = v;
  __syncthreads();
  for (int off = 1; off < 256; off <<= 1) {
    int x = (t >= off) ? tmp[t - off] : 0;
    __syncthreads();
    tmp[t] += x;
    __syncthreads();
  }
  if (gid < n) incl[gid] = tmp[t];
  if (t == 255) bsum[blockIdx.x] = tmp[255];
}

__global__ void scan_small(const int* __restrict__ bsum, int* __restrict__ bbase, int nb) {
  __shared__ int tmp[512];
  int t = threadIdx.x;
  int v = (t < nb) ? bsum[t] : 0;
  tmp[t] = v;
  __syncthreads();
  for (int off = 1; off < 512; off <<= 1) {
    int x = (t >= off) ? tmp[t - off] : 0;
    __syncthreads();
    tmp[t] += x;
    __syncthreads();
  }
  if (t < nb) bbase[t] = tmp[t] - v;  // exclusive
}

__global__ void finalize_offsets(const int* __restrict__ incl, const int* __restrict__ deg,
                                 const int* __restrict__ bbase, int* __restrict__ offsets,
                                 int n) {
  int gid = blockIdx.x * blockDim.x + threadIdx.x;
  if (gid >= n) return;
  int base = bbase[gid >> 8];
  offsets[gid] = incl[gid] - deg[gid] + base;
  if (gid == n - 1) offsets[n] = incl[gid] + base;
}

__global__ void scatter_edges(const int* __restrict__ src, const int* __restrict__ dst,
                              const int* __restrict__ offsets, int* __restrict__ cursor,
                              int* __restrict__ ssrc, int e) {
  int gid = blockIdx.x * blockDim.x + threadIdx.x;
  if (gid < e) {
    int d = dst[gid];
    int p = offsets[d] + atomicAdd(&cursor[d], 1);
    ssrc[p] = src[gid];
  }
}

// ---------------- wave-per-node online softmax (shared by both aggregates) ----------------
__device__ inline void wave_softmax_stats(const float* __restrict__ el, float er_h, int h,
                                          int strip, const int* __restrict__ ssrc, int s0,
                                          int s1, float& m, float& ss) {
  m = -INFINITY;
  ss = 0.f;
  for (int j = s0 + strip; j < s1; j += 8) {
    int s = ssrc[j];
    float x = el[s * HEADS + h] + er_h;
    x = x > 0.f ? x : SLOPE * x;
    if (x > m) {
      ss = ss * __expf(m - x) + 1.f;
      m = x;
    } else {
      ss += __expf(x - m);
    }
  }
#pragma unroll
  for (int mask = 1; mask < 8; mask <<= 1) {
    float mo = __shfl_xor(m, mask, 64);
    float so = __shfl_xor(ss, mask, 64);
    float mn = fmaxf(m, mo);
    float e1 = (m == -INFINITY) ? 0.f : __expf(m - mn);
    float e2 = (mo == -INFINITY) ? 0.f : __expf(mo - mn);
    ss = ss * e1 + so * e2;
    m = mn;
  }
}

// ---------------- layer-1 aggregate: HD=512, D=64, bf16 gather, relu, bf16 out ----------------
__global__ __launch_bounds__(256) void aggregate1(
    const bf16_t* __restrict__ featb, const float* __restrict__ el,
    const float* __restrict__ er, const int* __restrict__ offsets,
    const int* __restrict__ ssrc, const float* __restrict__ bias,
    bf16_t* __restrict__ outb, int n) {
  int wid = threadIdx.x >> 6, lane = threadIdx.x & 63;
  int node = blockIdx.x * 4 + wid;
  if (node >= n) return;
  int s0 = offsets[node], s1 = offsets[node + 1];
  int h = lane >> 3, strip = lane & 7;
  float er_h = er[node * HEADS + h];
  float m, ss;
  wave_softmax_stats(el, er_h, h, strip, ssrc, s0, s1, m, ss);
  float inv_ss = 1.f / ss;

  float acc[8] = {};
  for (int j = s0; j < s1; ++j) {
    int s = ssrc[j];
    float x = el[s * HEADS + h] + er_h;
    x = x > 0.f ? x : SLOPE * x;
    float alpha = __expf(x - m) * inv_ss;
    bf16x8 fv = *(const bf16x8*)(featb + (size_t)s * 512 + lane * 8);
#pragma unroll
    for (int i = 0; i < 8; ++i) acc[i] += alpha * (float)fv[i];
  }
  bf16x8 o;
#pragma unroll
  for (int i = 0; i < 8; ++i) {
    float v = acc[i] + bias[lane * 8 + i];
    o[i] = (bf16_t)fmaxf(v, 0.f);
  }
  *(bf16x8*)(outb + (size_t)node * 512 + lane * 8) = o;
}

// ---------------- layer-2 aggregate: HD=320, D=40, bf16 gather, fused head-mean ----------------
__global__ __launch_bounds__(256) void aggregate2(
    const bf16_t* __restrict__ featb, const float* __restrict__ el,
    const float* __restrict__ er, const int* __restrict__ offsets,
    const int* __restrict__ ssrc, const float* __restrict__ bias,
    float* __restrict__ out, int n) {
  __shared__ float red[4][320];
  int wid = threadIdx.x >> 6, lane = threadIdx.x & 63;
  int node = blockIdx.x * 4 + wid;
  if (node >= n) return;
  int s0 = offsets[node], s1 = offsets[node + 1];
  int h = lane >> 3, strip = lane & 7;
  float er_h = er[node * HEADS + h];
  float m, ss;
  wave_softmax_stats(el, er_h, h, strip, ssrc, s0, s1, m, ss);
  float inv_ss = 1.f / ss;

  int alane0 = ((lane + 0 * 64) / 40) * 8;
  int alane1 = ((lane + 1 * 64) / 40) * 8;
  int alane2 = ((lane + 2 * 64) / 40) * 8;
  int alane3 = ((lane + 3 * 64) / 40) * 8;
  int alane4 = ((lane + 4 * 64) / 40) * 8;

  float acc[5] = {};
  for (int j = s0; j < s1; ++j) {
    int s = ssrc[j];
    float x = el[s * HEADS + h] + er_h;
    x = x > 0.f ? x : SLOPE * x;
    float aown = __expf(x - m) * inv_ss;
    const bf16_t* fp = featb + (size_t)s * 320;
    acc[0] += __shfl(aown, alane0, 64) * (float)fp[lane];
    acc[1] += __shfl(aown, alane1, 64) * (float)fp[lane + 64];
    acc[2] += __shfl(aown, alane2, 64) * (float)fp[lane + 128];
    acc[3] += __shfl(aown, alane3, 64) * (float)fp[lane + 192];
    acc[4] += __shfl(aown, alane4, 64) * (float)fp[lane + 256];
  }
#pragma unroll
  for (int k = 0; k < 5; ++k) {
    int d = lane + k * 64;
    red[wid][d] = acc[k] + bias[d];
  }
  __builtin_amdgcn_wave_barrier();
  asm volatile("s_waitcnt lgkmcnt(0)" ::: "memory");
  __builtin_amdgcn_wave_barrier();
  if (lane < 40) {
    float s = 0.f;
#pragma unroll
    for (int hh = 0; hh < HEADS; ++hh) s += red[wid][hh * 40 + lane];
    out[(size_t)node * 40 + lane] = s * 0.125f;
  }
}

extern "C" void kernel_launch(void* const* d_in, const int* in_sizes, int n_in,
                              void* d_out, int out_size, void* d_ws, size_t ws_size,
                              hipStream_t stream) {
  const float* features = (const float*)d_in[0];
  const float* W1 = (const float*)d_in[1];
  const float* al1 = (const float*)d_in[2];
  const float* ar1 = (const float*)d_in[3];
  const float* b1 = (const float*)d_in[4];
  const float* W2 = (const float*)d_in[5];
  const float* al2 = (const float*)d_in[6];
  const float* ar2 = (const float*)d_in[7];
  const float* b2 = (const float*)d_in[8];
  const int* src = (const int*)d_in[9];
  const int* dst = (const int*)d_in[10];
  float* out = (float*)d_out;

  const int n = in_sizes[0] / 512;         // 100000
  const int e = in_sizes[9];               // 500000
  const int Mp = ((n + 127) / 128) * 128;  // 100096

  char* p = (char*)d_ws;
  auto alloc = [&](size_t bytes) {
    char* r = p;
    p += (bytes + 255) & ~(size_t)255;
    return r;
  };
  // RA: feat1b bf16 [n,512] (gemm L1 out; dead after aggregate1) -> feat2b bf16 [n,320].
  bf16_t* feat1b = (bf16_t*)alloc((size_t)n * 512 * 2);  // 102.4 MB
  bf16_t* feat2b = feat1b;
  // RB: hb bf16 [Mp,512] (aggregate1 out rows [0,n); pad rows zeroed once).
  bf16_t* hb = (bf16_t*)alloc((size_t)Mp * 512 * 2);  // 102.5 MB
  bf16_t* W1t = (bf16_t*)alloc((size_t)512 * 512 * 2);
  bf16_t* W2t = (bf16_t*)alloc((size_t)384 * 512 * 2);
  float* el1 = (float*)alloc((size_t)n * 8 * 4);
  float* er1 = (float*)alloc((size_t)n * 8 * 4);
  float* el2 = (float*)alloc((size_t)n * 8 * 4);
  float* er2 = (float*)alloc((size_t)n * 8 * 4);
  int* deg = (int*)alloc((size_t)n * 4);
  int* cursor = (int*)alloc((size_t)n * 4);
  int* incl = (int*)alloc((size_t)n * 4);
  int* offsets = (int*)alloc((size_t)(n + 1) * 4);
  int nb = (n + 255) / 256;
  int* bsum = (int*)alloc((size_t)nb * 4);
  int* bbase = (int*)alloc((size_t)nb * 4);
  int* ssrc = (int*)alloc((size_t)e * 4);
  // total ~212 MB

  hipMemsetAsync(deg, 0, (size_t)n * 4, stream);
  hipMemsetAsync(cursor, 0, (size_t)n * 4, stream);
  // hb pad rows (read by gemm L2 A-staging); W2t rows [336,384) (B pad; [320,336) by prep).
  hipMemsetAsync(hb + (size_t)n * 512, 0, (size_t)(Mp - n) * 512 * 2, stream);
  hipMemsetAsync(W2t + (size_t)336 * 512, 0, (size_t)48 * 512 * 2, stream);

  int eb = (e + 255) / 256;
  count_deg<<<eb, 256, 0, stream>>>(dst, deg, e);
  scan_block<<<nb, 256, 0, stream>>>(deg, incl, bsum, n);
  scan_small<<<1, 512, 0, stream>>>(bsum, bbase, nb);
  finalize_offsets<<<nb, 256, 0, stream>>>(incl, deg, bbase, offsets, n);
  scatter_edges<<<eb, 256, 0, stream>>>(src, dst, offsets, cursor, ssrc, e);

  // ---- weight prep (tiny; A1 read fp32 directly by gemm_af32) ----
  prep_weights<<<(512 * 512 + 320 * 512 + 8 * 512 + 255) / 256, 256, 0, stream>>>(
      W1, W2, al2, ar2, W1t, W2t);

  // ---- layer 1 ---- (fp32-A direct GEMM, fixed 16B-granule swizzle, el1/er1 fused)
  dim3 g1(512 / 128, Mp / 128);  // col tiles fastest
  gemm_af32<<<g1, 256, 0, stream>>>(features, W1t, feat1b, al1, ar1, el1, er1, n, 512, 512);
  aggregate1<<<(n + 3) / 4, 256, 0, stream>>>(feat1b, el1, er1, offsets, ssrc, b1, hb, n);

  // ---- layer 2 ---- (feat2b overwrites feat1b — dead; el2/er2 fused via Wel2 extra cols)
  dim3 g2(384 / 128, Mp / 128);
  gemm_bf16_l2<<<g2, 256, 0, stream>>>(hb, W2t, feat2b, el2, er2, n, 320, 512);
  aggregate2<<<(n + 3) / 4, 256, 0, stream>>>(feat2b, el2, er2, offsets, ssrc, b2, out, n);
}

// Round 15
// 507.697 us; speedup vs baseline: 1.0120x; 1.0120x over previous
//
#include <hip/hip_runtime.h>
#include <cstdint>
#include <cstddef>

#define SLOPE 0.2f
#define HEADS 8

typedef __bf16 bf16_t;
typedef __bf16 bf16x8 __attribute__((ext_vector_type(8)));
typedef float f32x4 __attribute__((ext_vector_type(4)));

// ---- merged operand prep: A fp32->bf16 (n8a vec8 elems), W1t/W2t transpose, Wel2/Wer2 ----
__global__ void prep_all(const float* __restrict__ in, bf16_t* __restrict__ outA, long n8,
                         const float* __restrict__ W1, const float* __restrict__ W2,
                         const float* __restrict__ al2, const float* __restrict__ ar2,
                         bf16_t* __restrict__ W1t, bf16_t* __restrict__ W2t) {
  long gid = (long)blockIdx.x * blockDim.x + threadIdx.x;
  if (gid < n8) {
    const float4* ip = (const float4*)in;
    float4 v0 = ip[gid * 2], v1 = ip[gid * 2 + 1];
    bf16x8 o;
    o[0] = (bf16_t)v0.x; o[1] = (bf16_t)v0.y; o[2] = (bf16_t)v0.z; o[3] = (bf16_t)v0.w;
    o[4] = (bf16_t)v1.x; o[5] = (bf16_t)v1.y; o[6] = (bf16_t)v1.z; o[7] = (bf16_t)v1.w;
    ((bf16x8*)outA)[gid] = o;
    return;
  }
  long g0 = gid - n8;
  if (g0 < 512 * 512) {
    int g = (int)g0;
    int nn = g >> 9, kk = g & 511;
    W1t[g] = (bf16_t)W1[(size_t)kk * 512 + nn];
  } else if (g0 < 512 * 512 + 320 * 512) {
    int g = (int)(g0 - 512 * 512);
    int nn = g >> 9, kk = g & 511;
    W2t[g] = (bf16_t)W2[(size_t)kk * 320 + nn];
  } else if (g0 < 512 * 512 + 320 * 512 + 8 * 512) {
    int g = (int)(g0 - (512 * 512 + 320 * 512));
    int h = g >> 9, k = g & 511;
    float a = 0.f, b = 0.f;
    for (int d = 0; d < 40; ++d) {
      float w = W2[(size_t)k * 320 + h * 40 + d];
      a = fmaf(w, al2[h * 40 + d], a);
      b = fmaf(w, ar2[h * 40 + d], b);
    }
    W2t[(size_t)(320 + h) * 512 + k] = (bf16_t)a;
    W2t[(size_t)(328 + h) * 512 + k] = (bf16_t)b;
  }
}

// ---------------- layer-1 GEMM: 128(M)x256(N) tile, BK=64, 8 waves (2m x 4n) ----------------
// Per-wave geometry identical to the proven 128x128 kernel (64x64 out, acc[4][4], 16B-granule
// XOR swizzle, global_load_lds). Block covers 2x the columns -> halves logical A traffic.
// el1/er1 fused: each wave's 64-col span == head hh = blockIdx.x*4 + wn.
__global__ __launch_bounds__(512) void gemm_bf16_l1(
    const bf16_t* __restrict__ A,   // [Mp][512] bf16 (pad rows zeroed)
    const bf16_t* __restrict__ Bt,  // [512][512] bf16
    bf16_t* __restrict__ Cb,        // [M][512] bf16
    const float* __restrict__ al, const float* __restrict__ ar,
    float* __restrict__ elp, float* __restrict__ erp,
    int M, int Nc, int K) {
  __shared__ __align__(16) unsigned char lds[49152];  // A: [0,16K), B: [16K,48K)
  const int tid = threadIdx.x;
  const int wid = tid >> 6, lane = tid & 63;
  const int wm = wid >> 2, wn = wid & 3;
  const int bm = blockIdx.y * 128, bn = blockIdx.x * 256;
  const int quad = lane >> 4, lrow = lane & 15;

  f32x4 acc[4][4] = {};

  // staging: chunk c covers rows [8c, 8c+8); lane -> row 8c+(lane>>3), 16B slot lane&7;
  // source k pre-swizzled: slot ^ (row&7), row&7 = lane>>3.
  const int st_row = lane >> 3;
  const int st_k = 8 * ((lane & 7) ^ (lane >> 3));
  const bf16_t* aSrc = A + (size_t)(bm + st_row) * K + st_k;
  const bf16_t* bSrc = Bt + (size_t)(bn + st_row) * K + st_k;

  const int xorv = (lrow & 7) << 4;
  const int aRdBase = (wm * 64 + lrow) * 128;
  const int bRdBase = (wn * 64 + lrow) * 128 + 16384;

  for (int k0 = 0; k0 < K; k0 += 64) {
    if (k0) __syncthreads();
#pragma unroll
    for (int i = 0; i < 2; ++i) {  // A: 16 chunks = 8 waves x 2
      __builtin_amdgcn_global_load_lds(
          (const __attribute__((address_space(1))) void*)(aSrc +
                                                          (size_t)((i * 8 + wid) * 8) * K + k0),
          (__attribute__((address_space(3))) void*)(lds + (i * 8 + wid) * 1024), 16, 0, 0);
    }
#pragma unroll
    for (int i = 0; i < 4; ++i) {  // B: 32 chunks = 8 waves x 4
      __builtin_amdgcn_global_load_lds(
          (const __attribute__((address_space(1))) void*)(bSrc +
                                                          (size_t)((i * 8 + wid) * 8) * K + k0),
          (__attribute__((address_space(3))) void*)(lds + 16384 + (i * 8 + wid) * 1024), 16, 0,
          0);
    }
    __syncthreads();
#pragma unroll
    for (int kk = 0; kk < 2; ++kk) {
      bf16x8 af[4], bfr[4];
      const int kb = (kk * 64 + quad * 16) ^ xorv;
#pragma unroll
      for (int mf = 0; mf < 4; ++mf)
        af[mf] = *(const bf16x8*)(lds + aRdBase + mf * 2048 + kb);
#pragma unroll
      for (int nf = 0; nf < 4; ++nf)
        bfr[nf] = *(const bf16x8*)(lds + bRdBase + nf * 2048 + kb);
#pragma unroll
      for (int mf = 0; mf < 4; ++mf)
#pragma unroll
        for (int nf = 0; nf < 4; ++nf)
          acc[mf][nf] =
              __builtin_amdgcn_mfma_f32_16x16x32_bf16(af[mf], bfr[nf], acc[mf][nf], 0, 0, 0);
    }
  }

  // C/D layout (verified m89/m91): col = lane&15, row = (lane>>4)*4 + reg
  const int crow0 = bm + wm * 64 + quad * 4;
  const int ccol0 = bn + wn * 64 + lrow;
#pragma unroll
  for (int mf = 0; mf < 4; ++mf) {
#pragma unroll
    for (int r2 = 0; r2 < 4; ++r2) {
      int row = crow0 + mf * 16 + r2;
      if (row < M) {
#pragma unroll
        for (int nf = 0; nf < 4; ++nf) {
          int col = ccol0 + nf * 16;
          if (col < Nc) Cb[(size_t)row * Nc + col] = (bf16_t)acc[mf][nf][r2];
        }
      }
    }
  }

  // fused el1/er1: wave's 64-col span == head hh
  {
    const int hh = (bn >> 6) + wn;
    float alv[4], arv[4];
#pragma unroll
    for (int nf = 0; nf < 4; ++nf) {
      alv[nf] = al[hh * 64 + lrow + nf * 16];
      arv[nf] = ar[hh * 64 + lrow + nf * 16];
    }
#pragma unroll
    for (int mf = 0; mf < 4; ++mf) {
#pragma unroll
      for (int r2 = 0; r2 < 4; ++r2) {
        float pe = 0.f, pr = 0.f;
#pragma unroll
        for (int nf = 0; nf < 4; ++nf) {
          float v = acc[mf][nf][r2];
          pe = fmaf(v, alv[nf], pe);
          pr = fmaf(v, arv[nf], pr);
        }
#pragma unroll
        for (int mask = 1; mask < 16; mask <<= 1) {
          pe += __shfl_xor(pe, mask, 64);
          pr += __shfl_xor(pr, mask, 64);
        }
        int row = crow0 + mf * 16 + r2;
        if (lrow == 0 && row < M) {
          elp[(size_t)row * 8 + hh] = pe;
          erp[(size_t)row * 8 + hh] = pr;
        }
      }
    }
  }
}

// ---------------- layer-2 GEMM: proven 128x128 kernel + fused el2/er2 epilogue ----------------
__global__ __launch_bounds__(256) void gemm_bf16_l2(
    const bf16_t* __restrict__ A,   // [Mp][K] bf16 (pad rows zeroed)
    const bf16_t* __restrict__ Bt,  // [384][K] bf16 (rows [336,384) zeroed)
    bf16_t* __restrict__ Cb,        // [M][320] bf16
    float* __restrict__ elp, float* __restrict__ erp,
    int M, int NcFeat, int K) {
  __shared__ __align__(16) unsigned char lds[32768];  // A: [0,16K), B: [16K,32K)
  const int tid = threadIdx.x;
  const int wid = tid >> 6, lane = tid & 63;
  const int wm = wid >> 1, wn = wid & 1;
  const int bm = blockIdx.y * 128, bn = blockIdx.x * 128;  // col tiles fastest
  const int quad = lane >> 4, lrow = lane & 15;

  f32x4 acc[4][4] = {};

  const int st_sub = wid * 8 + (lane >> 3);
  const int st_k = 8 * ((lane & 7) ^ (lane >> 3));
  const bf16_t* aSrc = A + (size_t)(bm + st_sub) * K + st_k;
  const bf16_t* bSrc = Bt + (size_t)(bn + st_sub) * K + st_k;

  const int xorv = (lrow & 7) << 4;
  const int aRdBase = (wm * 64 + lrow) * 128;
  const int bRdBase = (wn * 64 + lrow) * 128 + 16384;

  for (int k0 = 0; k0 < K; k0 += 64) {
    if (k0) __syncthreads();
#pragma unroll
    for (int i = 0; i < 4; ++i) {
      __builtin_amdgcn_global_load_lds(
          (const __attribute__((address_space(1))) void*)(aSrc + (size_t)i * 32 * K + k0),
          (__attribute__((address_space(3))) void*)(lds + (i * 4 + wid) * 1024), 16, 0, 0);
    }
#pragma unroll
    for (int i = 0; i < 4; ++i) {
      __builtin_amdgcn_global_load_lds(
          (const __attribute__((address_space(1))) void*)(bSrc + (size_t)i * 32 * K + k0),
          (__attribute__((address_space(3))) void*)(lds + 16384 + (i * 4 + wid) * 1024), 16, 0, 0);
    }
    __syncthreads();
#pragma unroll
    for (int kk = 0; kk < 2; ++kk) {
      bf16x8 af[4], bfr[4];
      const int kb = (kk * 64 + quad * 16) ^ xorv;
#pragma unroll
      for (int mf = 0; mf < 4; ++mf)
        af[mf] = *(const bf16x8*)(lds + aRdBase + mf * 2048 + kb);
#pragma unroll
      for (int nf = 0; nf < 4; ++nf)
        bfr[nf] = *(const bf16x8*)(lds + bRdBase + nf * 2048 + kb);
#pragma unroll
      for (int mf = 0; mf < 4; ++mf)
#pragma unroll
        for (int nf = 0; nf < 4; ++nf)
          acc[mf][nf] =
              __builtin_amdgcn_mfma_f32_16x16x32_bf16(af[mf], bfr[nf], acc[mf][nf], 0, 0, 0);
    }
  }

  const int crow0 = bm + wm * 64 + quad * 4;
  const int ccol0 = bn + wn * 64 + lrow;
#pragma unroll
  for (int mf = 0; mf < 4; ++mf) {
#pragma unroll
    for (int r2 = 0; r2 < 4; ++r2) {
      int row = crow0 + mf * 16 + r2;
      if (row < M) {
#pragma unroll
        for (int nf = 0; nf < 4; ++nf) {
          int col = ccol0 + nf * 16;
          float v = acc[mf][nf][r2];
          if (col < NcFeat) {
            Cb[(size_t)row * NcFeat + col] = (bf16_t)v;
          } else if (col < NcFeat + 8) {
            elp[(size_t)row * 8 + (col - NcFeat)] = v;
          } else if (col < NcFeat + 16) {
            erp[(size_t)row * 8 + (col - NcFeat - 8)] = v;
          }
        }
      }
    }
  }
}

// ---------------- CSR build ----------------
__global__ void count_deg(const int* __restrict__ dst, int* __restrict__ deg, int e) {
  int gid = blockIdx.x * blockDim.x + threadIdx.x;
  if (gid < e) atomicAdd(&deg[dst[gid]], 1);
}

__global__ void scan_block(const int* __restrict__ deg, int* __restrict__ incl,
                           int* __restrict__ bsum, int n) {
  __shared__ int tmp[256];
  int t = threadIdx.x;
  int gid = blockIdx.x * 256 + t;
  int v = (gid < n) ? deg[gid] : 0;
  tmp[t] = v;
  __syncthreads();
  for (int off = 1; off < 256; off <<= 1) {
    int x = (t >= off) ? tmp[t - off] : 0;
    __syncthreads();
    tmp[t] += x;
    __syncthreads();
  }
  if (gid < n) incl[gid] = tmp[t];
  if (t == 255) bsum[blockIdx.x] = tmp[255];
}

__global__ void scan_small(const int* __restrict__ bsum, int* __restrict__ bbase, int nb) {
  __shared__ int tmp[512];
  int t = threadIdx.x;
  int v = (t < nb) ? bsum[t] : 0;
  tmp[t] = v;
  __syncthreads();
  for (int off = 1; off < 512; off <<= 1) {
    int x = (t >= off) ? tmp[t - off] : 0;
    __syncthreads();
    tmp[t] += x;
    __syncthreads();
  }
  if (t < nb) bbase[t] = tmp[t] - v;  // exclusive
}

__global__ void finalize_offsets(const int* __restrict__ incl, const int* __restrict__ deg,
                                 const int* __restrict__ bbase, int* __restrict__ offsets,
                                 int n) {
  int gid = blockIdx.x * blockDim.x + threadIdx.x;
  if (gid >= n) return;
  int base = bbase[gid >> 8];
  offsets[gid] = incl[gid] - deg[gid] + base;
  if (gid == n - 1) offsets[n] = incl[gid] + base;
}

__global__ void scatter_edges(const int* __restrict__ src, const int* __restrict__ dst,
                              const int* __restrict__ offsets, int* __restrict__ cursor,
                              int* __restrict__ ssrc, int e) {
  int gid = blockIdx.x * blockDim.x + threadIdx.x;
  if (gid < e) {
    int d = dst[gid];
    int p = offsets[d] + atomicAdd(&cursor[d], 1);
    ssrc[p] = src[gid];
  }
}

// ---------------- wave-per-node online softmax (shared by both aggregates) ----------------
__device__ inline void wave_softmax_stats(const float* __restrict__ el, float er_h, int h,
                                          int strip, const int* __restrict__ ssrc, int s0,
                                          int s1, float& m, float& ss) {
  m = -INFINITY;
  ss = 0.f;
  for (int j = s0 + strip; j < s1; j += 8) {
    int s = ssrc[j];
    float x = el[s * HEADS + h] + er_h;
    x = x > 0.f ? x : SLOPE * x;
    if (x > m) {
      ss = ss * __expf(m - x) + 1.f;
      m = x;
    } else {
      ss += __expf(x - m);
    }
  }
#pragma unroll
  for (int mask = 1; mask < 8; mask <<= 1) {
    float mo = __shfl_xor(m, mask, 64);
    float so = __shfl_xor(ss, mask, 64);
    float mn = fmaxf(m, mo);
    float e1 = (m == -INFINITY) ? 0.f : __expf(m - mn);
    float e2 = (mo == -INFINITY) ? 0.f : __expf(mo - mn);
    ss = ss * e1 + so * e2;
    m = mn;
  }
}

// ---------------- layer-1 aggregate: HD=512, D=64, bf16 gather, relu, bf16 out ----------------
__global__ __launch_bounds__(256) void aggregate1(
    const bf16_t* __restrict__ featb, const float* __restrict__ el,
    const float* __restrict__ er, const int* __restrict__ offsets,
    const int* __restrict__ ssrc, const float* __restrict__ bias,
    bf16_t* __restrict__ outb, int n) {
  int wid = threadIdx.x >> 6, lane = threadIdx.x & 63;
  int node = blockIdx.x * 4 + wid;
  if (node >= n) return;
  int s0 = offsets[node], s1 = offsets[node + 1];
  int h = lane >> 3, strip = lane & 7;
  float er_h = er[node * HEADS + h];
  float m, ss;
  wave_softmax_stats(el, er_h, h, strip, ssrc, s0, s1, m, ss);
  float inv_ss = 1.f / ss;

  float acc[8] = {};
  for (int j = s0; j < s1; ++j) {
    int s = ssrc[j];
    float x = el[s * HEADS + h] + er_h;
    x = x > 0.f ? x : SLOPE * x;
    float alpha = __expf(x - m) * inv_ss;
    bf16x8 fv = *(const bf16x8*)(featb + (size_t)s * 512 + lane * 8);
#pragma unroll
    for (int i = 0; i < 8; ++i) acc[i] += alpha * (float)fv[i];
  }
  bf16x8 o;
#pragma unroll
  for (int i = 0; i < 8; ++i) {
    float v = acc[i] + bias[lane * 8 + i];
    o[i] = (bf16_t)fmaxf(v, 0.f);
  }
  *(bf16x8*)(outb + (size_t)node * 512 + lane * 8) = o;
}

// ---------------- layer-2 aggregate: HD=320, D=40, bf16 gather, fused head-mean ----------------
__global__ __launch_bounds__(256) void aggregate2(
    const bf16_t* __restrict__ featb, const float* __restrict__ el,
    const float* __restrict__ er, const int* __restrict__ offsets,
    const int* __restrict__ ssrc, const float* __restrict__ bias,
    float* __restrict__ out, int n) {
  __shared__ float red[4][320];
  int wid = threadIdx.x >> 6, lane = threadIdx.x & 63;
  int node = blockIdx.x * 4 + wid;
  if (node >= n) return;
  int s0 = offsets[node], s1 = offsets[node + 1];
  int h = lane >> 3, strip = lane & 7;
  float er_h = er[node * HEADS + h];
  float m, ss;
  wave_softmax_stats(el, er_h, h, strip, ssrc, s0, s1, m, ss);
  float inv_ss = 1.f / ss;

  int alane0 = ((lane + 0 * 64) / 40) * 8;
  int alane1 = ((lane + 1 * 64) / 40) * 8;
  int alane2 = ((lane + 2 * 64) / 40) * 8;
  int alane3 = ((lane + 3 * 64) / 40) * 8;
  int alane4 = ((lane + 4 * 64) / 40) * 8;

  float acc[5] = {};
  for (int j = s0; j < s1; ++j) {
    int s = ssrc[j];
    float x = el[s * HEADS + h] + er_h;
    x = x > 0.f ? x : SLOPE * x;
    float aown = __expf(x - m) * inv_ss;
    const bf16_t* fp = featb + (size_t)s * 320;
    acc[0] += __shfl(aown, alane0, 64) * (float)fp[lane];
    acc[1] += __shfl(aown, alane1, 64) * (float)fp[lane + 64];
    acc[2] += __shfl(aown, alane2, 64) * (float)fp[lane + 128];
    acc[3] += __shfl(aown, alane3, 64) * (float)fp[lane + 192];
    acc[4] += __shfl(aown, alane4, 64) * (float)fp[lane + 256];
  }
#pragma unroll
  for (int k = 0; k < 5; ++k) {
    int d = lane + k * 64;
    red[wid][d] = acc[k] + bias[d];
  }
  __builtin_amdgcn_wave_barrier();
  asm volatile("s_waitcnt lgkmcnt(0)" ::: "memory");
  __builtin_amdgcn_wave_barrier();
  if (lane < 40) {
    float s = 0.f;
#pragma unroll
    for (int hh = 0; hh < HEADS; ++hh) s += red[wid][hh * 40 + lane];
    out[(size_t)node * 40 + lane] = s * 0.125f;
  }
}

extern "C" void kernel_launch(void* const* d_in, const int* in_sizes, int n_in,
                              void* d_out, int out_size, void* d_ws, size_t ws_size,
                              hipStream_t stream) {
  const float* features = (const float*)d_in[0];
  const float* W1 = (const float*)d_in[1];
  const float* al1 = (const float*)d_in[2];
  const float* ar1 = (const float*)d_in[3];
  const float* b1 = (const float*)d_in[4];
  const float* W2 = (const float*)d_in[5];
  const float* al2 = (const float*)d_in[6];
  const float* ar2 = (const float*)d_in[7];
  const float* b2 = (const float*)d_in[8];
  const int* src = (const int*)d_in[9];
  const int* dst = (const int*)d_in[10];
  float* out = (float*)d_out;

  const int n = in_sizes[0] / 512;         // 100000
  const int e = in_sizes[9];               // 500000
  const int Mp = ((n + 127) / 128) * 128;  // 100096

  char* p = (char*)d_ws;
  auto alloc = [&](size_t bytes) {
    char* r = p;
    p += (bytes + 255) & ~(size_t)255;
    return r;
  };
  // RA: feat1b bf16 [n,512] (gemm L1 out; dead after aggregate1) -> feat2b bf16 [n,320].
  bf16_t* feat1b = (bf16_t*)alloc((size_t)n * 512 * 2);  // 102.4 MB
  bf16_t* feat2b = feat1b;
  // RB: A1b bf16 [Mp,512] (prep out, gemm L1 in; dead after gemm L1)
  //     -> hb bf16 [Mp,512] (aggregate1 out rows [0,n); pad rows stay zeroed from A1b init).
  bf16_t* A1b = (bf16_t*)alloc((size_t)Mp * 512 * 2);  // 102.5 MB
  bf16_t* hb = A1b;
  bf16_t* W1t = (bf16_t*)alloc((size_t)512 * 512 * 2);
  bf16_t* W2t = (bf16_t*)alloc((size_t)384 * 512 * 2);
  float* el1 = (float*)alloc((size_t)n * 8 * 4);
  float* er1 = (float*)alloc((size_t)n * 8 * 4);
  float* el2 = (float*)alloc((size_t)n * 8 * 4);
  float* er2 = (float*)alloc((size_t)n * 8 * 4);
  int* deg = (int*)alloc((size_t)n * 4);
  int* cursor = (int*)alloc((size_t)n * 4);
  int* incl = (int*)alloc((size_t)n * 4);
  int* offsets = (int*)alloc((size_t)(n + 1) * 4);
  int nb = (n + 255) / 256;
  int* bsum = (int*)alloc((size_t)nb * 4);
  int* bbase = (int*)alloc((size_t)nb * 4);
  int* ssrc = (int*)alloc((size_t)e * 4);
  // total ~215 MB

  hipMemsetAsync(deg, 0, (size_t)n * 4, stream);
  hipMemsetAsync(cursor, 0, (size_t)n * 4, stream);
  // A1b/hb pad rows (read by gemm A-staging); W2t rows [336,384) (B pad; [320,336) by prep).
  hipMemsetAsync(A1b + (size_t)n * 512, 0, (size_t)(Mp - n) * 512 * 2, stream);
  hipMemsetAsync(W2t + (size_t)336 * 512, 0, (size_t)48 * 512 * 2, stream);

  int eb = (e + 255) / 256;
  count_deg<<<eb, 256, 0, stream>>>(dst, deg, e);
  scan_block<<<nb, 256, 0, stream>>>(deg, incl, bsum, n);
  scan_small<<<1, 512, 0, stream>>>(bsum, bbase, nb);
  finalize_offsets<<<nb, 256, 0, stream>>>(incl, deg, bbase, offsets, n);
  scatter_edges<<<eb, 256, 0, stream>>>(src, dst, offsets, cursor, ssrc, e);

  // ---- merged operand prep (A bf16 + W1t + W2t + Wel2/Wer2, one launch) ----
  long n8a = (long)n * 512 / 8;  // 6.4M
  long prep_total = n8a + 512 * 512 + 320 * 512 + 8 * 512;
  prep_all<<<(int)((prep_total + 255) / 256), 256, 0, stream>>>(
      features, A1b, n8a, W1, W2, al2, ar2, W1t, W2t);

  // ---- layer 1 ---- (128x256 tile, 8 waves; el1/er1 fused into epilogue)
  dim3 g1(512 / 256, Mp / 128);
  gemm_bf16_l1<<<g1, 512, 0, stream>>>(A1b, W1t, feat1b, al1, ar1, el1, er1, n, 512, 512);
  aggregate1<<<(n + 3) / 4, 256, 0, stream>>>(feat1b, el1, er1, offsets, ssrc, b1, hb, n);

  // ---- layer 2 ---- (feat2b overwrites feat1b — dead; el2/er2 fused via Wel2 extra cols)
  dim3 g2(384 / 128, Mp / 128);
  gemm_bf16_l2<<<g2, 256, 0, stream>>>(hb, W2t, feat2b, el2, er2, n, 320, 512);
  aggregate2<<<(n + 3) / 4, 256, 0, stream>>>(feat2b, el2, er2, offsets, ssrc, b2, out, n);
}

// Round 16
// 488.664 us; speedup vs baseline: 1.0514x; 1.0389x over previous
//
#include <hip/hip_runtime.h>
#include <cstdint>
#include <cstddef>

#define SLOPE 0.2f
#define HEADS 8

typedef __bf16 bf16_t;
typedef __bf16 bf16x8 __attribute__((ext_vector_type(8)));
typedef float f32x4 __attribute__((ext_vector_type(4)));

// ---- merged operand prep: A fp32->bf16 (n8a vec8 elems), W1t/W2t transpose, Wel2/Wer2 ----
__global__ void prep_all(const float* __restrict__ in, bf16_t* __restrict__ outA, long n8,
                         const float* __restrict__ W1, const float* __restrict__ W2,
                         const float* __restrict__ al2, const float* __restrict__ ar2,
                         bf16_t* __restrict__ W1t, bf16_t* __restrict__ W2t) {
  long gid = (long)blockIdx.x * blockDim.x + threadIdx.x;
  if (gid < n8) {
    const float4* ip = (const float4*)in;
    float4 v0 = ip[gid * 2], v1 = ip[gid * 2 + 1];
    bf16x8 o;
    o[0] = (bf16_t)v0.x; o[1] = (bf16_t)v0.y; o[2] = (bf16_t)v0.z; o[3] = (bf16_t)v0.w;
    o[4] = (bf16_t)v1.x; o[5] = (bf16_t)v1.y; o[6] = (bf16_t)v1.z; o[7] = (bf16_t)v1.w;
    ((bf16x8*)outA)[gid] = o;
    return;
  }
  long g0 = gid - n8;
  if (g0 < 512 * 512) {
    int g = (int)g0;
    int nn = g >> 9, kk = g & 511;
    W1t[g] = (bf16_t)W1[(size_t)kk * 512 + nn];
  } else if (g0 < 512 * 512 + 320 * 512) {
    int g = (int)(g0 - 512 * 512);
    int nn = g >> 9, kk = g & 511;
    W2t[g] = (bf16_t)W2[(size_t)kk * 320 + nn];
  } else if (g0 < 512 * 512 + 320 * 512 + 8 * 512) {
    int g = (int)(g0 - (512 * 512 + 320 * 512));
    int h = g >> 9, k = g & 511;
    float a = 0.f, b = 0.f;
    for (int d = 0; d < 40; ++d) {
      float w = W2[(size_t)k * 320 + h * 40 + d];
      a = fmaf(w, al2[h * 40 + d], a);
      b = fmaf(w, ar2[h * 40 + d], b);
    }
    W2t[(size_t)(320 + h) * 512 + k] = (bf16_t)a;
    W2t[(size_t)(328 + h) * 512 + k] = (bf16_t)b;
  }
}

// ---------------- bf16 MFMA GEMM: Cb[M,NcFeat] = A[Mp,K] * Bt[Np,K]^T ----------------
// 128x128 tile, BK=64, 4 waves (2x2), global_load_lds staging, pre-swizzled-source XOR LDS
// (16B granule — conflict-free). Col tiles fastest (blockIdx.x) for A L2/L3 reuse.
// MODE 0 (layer 1): el/er computed in-epilogue from fp32 acc (wave's 64-col span == head).
// MODE 1 (layer 2): cols [NcFeat,NcFeat+8) -> elp, [NcFeat+8,NcFeat+16) -> erp (Wel2 rows).
template <int MODE>
__global__ __launch_bounds__(256) void gemm_bf16(
    const bf16_t* __restrict__ A,   // [Mp][K] bf16 (pad rows zeroed)
    const bf16_t* __restrict__ Bt,  // [Np][K] bf16 (rows beyond use zeroed)
    bf16_t* __restrict__ Cb,        // [M][NcFeat] bf16
    const float* __restrict__ al, const float* __restrict__ ar,  // MODE 0 only
    float* __restrict__ elp, float* __restrict__ erp,
    int M, int NcFeat, int K) {
  __shared__ __align__(16) unsigned char lds[32768];  // A: [0,16K), B: [16K,32K)
  const int tid = threadIdx.x;
  const int wid = tid >> 6, lane = tid & 63;
  const int wm = wid >> 1, wn = wid & 1;
  const int bm = blockIdx.y * 128, bn = blockIdx.x * 128;  // col tiles fastest
  const int quad = lane >> 4, lrow = lane & 15;

  f32x4 acc[4][4] = {};

  const int st_sub = wid * 8 + (lane >> 3);
  const int st_k = 8 * ((lane & 7) ^ (lane >> 3));
  const bf16_t* aSrc = A + (size_t)(bm + st_sub) * K + st_k;
  const bf16_t* bSrc = Bt + (size_t)(bn + st_sub) * K + st_k;

  const int xorv = (lrow & 7) << 4;
  const int aRdBase = (wm * 64 + lrow) * 128;
  const int bRdBase = (wn * 64 + lrow) * 128 + 16384;

  for (int k0 = 0; k0 < K; k0 += 64) {
    if (k0) __syncthreads();
#pragma unroll
    for (int i = 0; i < 4; ++i) {
      __builtin_amdgcn_global_load_lds(
          (const __attribute__((address_space(1))) void*)(aSrc + (size_t)i * 32 * K + k0),
          (__attribute__((address_space(3))) void*)(lds + (i * 4 + wid) * 1024), 16, 0, 0);
    }
#pragma unroll
    for (int i = 0; i < 4; ++i) {
      __builtin_amdgcn_global_load_lds(
          (const __attribute__((address_space(1))) void*)(bSrc + (size_t)i * 32 * K + k0),
          (__attribute__((address_space(3))) void*)(lds + 16384 + (i * 4 + wid) * 1024), 16, 0, 0);
    }
    __syncthreads();
#pragma unroll
    for (int kk = 0; kk < 2; ++kk) {
      bf16x8 af[4], bfr[4];
      const int kb = (kk * 64 + quad * 16) ^ xorv;
#pragma unroll
      for (int mf = 0; mf < 4; ++mf)
        af[mf] = *(const bf16x8*)(lds + aRdBase + mf * 2048 + kb);
#pragma unroll
      for (int nf = 0; nf < 4; ++nf)
        bfr[nf] = *(const bf16x8*)(lds + bRdBase + nf * 2048 + kb);
#pragma unroll
      for (int mf = 0; mf < 4; ++mf)
#pragma unroll
        for (int nf = 0; nf < 4; ++nf)
          acc[mf][nf] =
              __builtin_amdgcn_mfma_f32_16x16x32_bf16(af[mf], bfr[nf], acc[mf][nf], 0, 0, 0);
    }
  }

  // C/D layout (verified m89/m91): col = lane&15, row = (lane>>4)*4 + reg
  const int crow0 = bm + wm * 64 + quad * 4;
  const int ccol0 = bn + wn * 64 + lrow;
#pragma unroll
  for (int mf = 0; mf < 4; ++mf) {
#pragma unroll
    for (int r2 = 0; r2 < 4; ++r2) {
      int row = crow0 + mf * 16 + r2;
      if (row < M) {
#pragma unroll
        for (int nf = 0; nf < 4; ++nf) {
          int col = ccol0 + nf * 16;
          float v = acc[mf][nf][r2];
          if (col < NcFeat) {
            Cb[(size_t)row * NcFeat + col] = (bf16_t)v;
          } else if (MODE == 1) {
            if (col < NcFeat + 8) elp[(size_t)row * 8 + (col - NcFeat)] = v;
            else if (col < NcFeat + 16) erp[(size_t)row * 8 + (col - NcFeat - 8)] = v;
          }
        }
      }
    }
  }

  if (MODE == 0) {
    // this wave's 64-col span == head hh; el/er from fp32 acc, 16-lane reduce per row
    const int hh = (bn >> 6) + wn;
    float alv[4], arv[4];
#pragma unroll
    for (int nf = 0; nf < 4; ++nf) {
      alv[nf] = al[hh * 64 + lrow + nf * 16];
      arv[nf] = ar[hh * 64 + lrow + nf * 16];
    }
#pragma unroll
    for (int mf = 0; mf < 4; ++mf) {
#pragma unroll
      for (int r2 = 0; r2 < 4; ++r2) {
        float pe = 0.f, pr = 0.f;
#pragma unroll
        for (int nf = 0; nf < 4; ++nf) {
          float v = acc[mf][nf][r2];
          pe = fmaf(v, alv[nf], pe);
          pr = fmaf(v, arv[nf], pr);
        }
#pragma unroll
        for (int mask = 1; mask < 16; mask <<= 1) {
          pe += __shfl_xor(pe, mask, 64);
          pr += __shfl_xor(pr, mask, 64);
        }
        int row = crow0 + mf * 16 + r2;
        if (lrow == 0 && row < M) {
          elp[(size_t)row * 8 + hh] = pe;
          erp[(size_t)row * 8 + hh] = pr;
        }
      }
    }
  }
}

// ---------------- CSR build ----------------
__global__ void count_deg(const int* __restrict__ dst, int* __restrict__ deg, int e) {
  int gid = blockIdx.x * blockDim.x + threadIdx.x;
  if (gid < e) atomicAdd(&deg[dst[gid]], 1);
}

__global__ void scan_block(const int* __restrict__ deg, int* __restrict__ incl,
                           int* __restrict__ bsum, int n) {
  __shared__ int tmp[256];
  int t = threadIdx.x;
  int gid = blockIdx.x * 256 + t;
  int v = (gid < n) ? deg[gid] : 0;
  tmp[t] = v;
  __syncthreads();
  for (int off = 1; off < 256; off <<= 1) {
    int x = (t >= off) ? tmp[t - off] : 0;
    __syncthreads();
    tmp[t] += x;
    __syncthreads();
  }
  if (gid < n) incl[gid] = tmp[t];
  if (t == 255) bsum[blockIdx.x] = tmp[255];
}

__global__ void scan_small(const int* __restrict__ bsum, int* __restrict__ bbase, int nb) {
  __shared__ int tmp[512];
  int t = threadIdx.x;
  int v = (t < nb) ? bsum[t] : 0;
  tmp[t] = v;
  __syncthreads();
  for (int off = 1; off < 512; off <<= 1) {
    int x = (t >= off) ? tmp[t - off] : 0;
    __syncthreads();
    tmp[t] += x;
    __syncthreads();
  }
  if (t < nb) bbase[t] = tmp[t] - v;  // exclusive
}

__global__ void finalize_offsets(const int* __restrict__ incl, const int* __restrict__ deg,
                                 const int* __restrict__ bbase, int* __restrict__ offsets,
                                 int n) {
  int gid = blockIdx.x * blockDim.x + threadIdx.x;
  if (gid >= n) return;
  int base = bbase[gid >> 8];
  offsets[gid] = incl[gid] - deg[gid] + base;
  if (gid == n - 1) offsets[n] = incl[gid] + base;
}

__global__ void scatter_edges(const int* __restrict__ src, const int* __restrict__ dst,
                              const int* __restrict__ offsets, int* __restrict__ cursor,
                              int* __restrict__ ssrc, int e) {
  int gid = blockIdx.x * blockDim.x + threadIdx.x;
  if (gid < e) {
    int d = dst[gid];
    int p = offsets[d] + atomicAdd(&cursor[d], 1);
    ssrc[p] = src[gid];
  }
}

// ---------------- wave-per-node online softmax (shared by both aggregates) ----------------
__device__ inline void wave_softmax_stats(const float* __restrict__ el, float er_h, int h,
                                          int strip, const int* __restrict__ ssrc, int s0,
                                          int s1, float& m, float& ss) {
  m = -INFINITY;
  ss = 0.f;
  for (int j = s0 + strip; j < s1; j += 8) {
    int s = ssrc[j];
    float x = el[s * HEADS + h] + er_h;
    x = x > 0.f ? x : SLOPE * x;
    if (x > m) {
      ss = ss * __expf(m - x) + 1.f;
      m = x;
    } else {
      ss += __expf(x - m);
    }
  }
#pragma unroll
  for (int mask = 1; mask < 8; mask <<= 1) {
    float mo = __shfl_xor(m, mask, 64);
    float so = __shfl_xor(ss, mask, 64);
    float mn = fmaxf(m, mo);
    float e1 = (m == -INFINITY) ? 0.f : __expf(m - mn);
    float e2 = (mo == -INFINITY) ? 0.f : __expf(mo - mn);
    ss = ss * e1 + so * e2;
    m = mn;
  }
}

// ---------------- layer-1 aggregate: HD=512, D=64, bf16 gather, relu, bf16 out ----------------
// Weighted pass 4-edge unrolled: 4 independent 16B gathers in flight per iteration (ILP fix
// for the 1-load dependent chain). Accumulation order preserved (sequential += per edge).
__global__ __launch_bounds__(256) void aggregate1(
    const bf16_t* __restrict__ featb, const float* __restrict__ el,
    const float* __restrict__ er, const int* __restrict__ offsets,
    const int* __restrict__ ssrc, const float* __restrict__ bias,
    bf16_t* __restrict__ outb, int n) {
  int wid = threadIdx.x >> 6, lane = threadIdx.x & 63;
  int node = blockIdx.x * 4 + wid;
  if (node >= n) return;
  int s0 = offsets[node], s1 = offsets[node + 1];
  int h = lane >> 3, strip = lane & 7;
  float er_h = er[node * HEADS + h];
  float m, ss;
  wave_softmax_stats(el, er_h, h, strip, ssrc, s0, s1, m, ss);
  float inv_ss = 1.f / ss;

  float acc[8] = {};
  int j = s0;
  for (; j + 3 < s1; j += 4) {
    int sa = ssrc[j], sb = ssrc[j + 1], sc = ssrc[j + 2], sd = ssrc[j + 3];
    float xa = el[sa * HEADS + h] + er_h; xa = xa > 0.f ? xa : SLOPE * xa;
    float xb = el[sb * HEADS + h] + er_h; xb = xb > 0.f ? xb : SLOPE * xb;
    float xc = el[sc * HEADS + h] + er_h; xc = xc > 0.f ? xc : SLOPE * xc;
    float xd = el[sd * HEADS + h] + er_h; xd = xd > 0.f ? xd : SLOPE * xd;
    float aa = __expf(xa - m) * inv_ss;
    float ab = __expf(xb - m) * inv_ss;
    float ac = __expf(xc - m) * inv_ss;
    float ad = __expf(xd - m) * inv_ss;
    bf16x8 fa = *(const bf16x8*)(featb + (size_t)sa * 512 + lane * 8);
    bf16x8 fb = *(const bf16x8*)(featb + (size_t)sb * 512 + lane * 8);
    bf16x8 fc = *(const bf16x8*)(featb + (size_t)sc * 512 + lane * 8);
    bf16x8 fd = *(const bf16x8*)(featb + (size_t)sd * 512 + lane * 8);
#pragma unroll
    for (int i = 0; i < 8; ++i) {
      acc[i] += aa * (float)fa[i];
      acc[i] += ab * (float)fb[i];
      acc[i] += ac * (float)fc[i];
      acc[i] += ad * (float)fd[i];
    }
  }
  for (; j < s1; ++j) {
    int s = ssrc[j];
    float x = el[s * HEADS + h] + er_h;
    x = x > 0.f ? x : SLOPE * x;
    float alpha = __expf(x - m) * inv_ss;
    bf16x8 fv = *(const bf16x8*)(featb + (size_t)s * 512 + lane * 8);
#pragma unroll
    for (int i = 0; i < 8; ++i) acc[i] += alpha * (float)fv[i];
  }
  bf16x8 o;
#pragma unroll
  for (int i = 0; i < 8; ++i) {
    float v = acc[i] + bias[lane * 8 + i];
    o[i] = (bf16_t)fmaxf(v, 0.f);
  }
  *(bf16x8*)(outb + (size_t)node * 512 + lane * 8) = o;
}

// ---------------- layer-2 aggregate: HD=320, D=40, bf16 gather, fused head-mean ----------------
__global__ __launch_bounds__(256) void aggregate2(
    const bf16_t* __restrict__ featb, const float* __restrict__ el,
    const float* __restrict__ er, const int* __restrict__ offsets,
    const int* __restrict__ ssrc, const float* __restrict__ bias,
    float* __restrict__ out, int n) {
  __shared__ float red[4][320];
  int wid = threadIdx.x >> 6, lane = threadIdx.x & 63;
  int node = blockIdx.x * 4 + wid;
  if (node >= n) return;
  int s0 = offsets[node], s1 = offsets[node + 1];
  int h = lane >> 3, strip = lane & 7;
  float er_h = er[node * HEADS + h];
  float m, ss;
  wave_softmax_stats(el, er_h, h, strip, ssrc, s0, s1, m, ss);
  float inv_ss = 1.f / ss;

  int alane0 = ((lane + 0 * 64) / 40) * 8;
  int alane1 = ((lane + 1 * 64) / 40) * 8;
  int alane2 = ((lane + 2 * 64) / 40) * 8;
  int alane3 = ((lane + 3 * 64) / 40) * 8;
  int alane4 = ((lane + 4 * 64) / 40) * 8;

  float acc[5] = {};
  for (int j = s0; j < s1; ++j) {
    int s = ssrc[j];
    float x = el[s * HEADS + h] + er_h;
    x = x > 0.f ? x : SLOPE * x;
    float aown = __expf(x - m) * inv_ss;
    const bf16_t* fp = featb + (size_t)s * 320;
    acc[0] += __shfl(aown, alane0, 64) * (float)fp[lane];
    acc[1] += __shfl(aown, alane1, 64) * (float)fp[lane + 64];
    acc[2] += __shfl(aown, alane2, 64) * (float)fp[lane + 128];
    acc[3] += __shfl(aown, alane3, 64) * (float)fp[lane + 192];
    acc[4] += __shfl(aown, alane4, 64) * (float)fp[lane + 256];
  }
#pragma unroll
  for (int k = 0; k < 5; ++k) {
    int d = lane + k * 64;
    red[wid][d] = acc[k] + bias[d];
  }
  __builtin_amdgcn_wave_barrier();
  asm volatile("s_waitcnt lgkmcnt(0)" ::: "memory");
  __builtin_amdgcn_wave_barrier();
  if (lane < 40) {
    float s = 0.f;
#pragma unroll
    for (int hh = 0; hh < HEADS; ++hh) s += red[wid][hh * 40 + lane];
    out[(size_t)node * 40 + lane] = s * 0.125f;
  }
}

extern "C" void kernel_launch(void* const* d_in, const int* in_sizes, int n_in,
                              void* d_out, int out_size, void* d_ws, size_t ws_size,
                              hipStream_t stream) {
  const float* features = (const float*)d_in[0];
  const float* W1 = (const float*)d_in[1];
  const float* al1 = (const float*)d_in[2];
  const float* ar1 = (const float*)d_in[3];
  const float* b1 = (const float*)d_in[4];
  const float* W2 = (const float*)d_in[5];
  const float* al2 = (const float*)d_in[6];
  const float* ar2 = (const float*)d_in[7];
  const float* b2 = (const float*)d_in[8];
  const int* src = (const int*)d_in[9];
  const int* dst = (const int*)d_in[10];
  float* out = (float*)d_out;

  const int n = in_sizes[0] / 512;         // 100000
  const int e = in_sizes[9];               // 500000
  const int Mp = ((n + 127) / 128) * 128;  // 100096

  char* p = (char*)d_ws;
  auto alloc = [&](size_t bytes) {
    char* r = p;
    p += (bytes + 255) & ~(size_t)255;
    return r;
  };
  // RA: feat1b bf16 [n,512] (gemm L1 out; dead after aggregate1) -> feat2b bf16 [n,320].
  bf16_t* feat1b = (bf16_t*)alloc((size_t)n * 512 * 2);  // 102.4 MB
  bf16_t* feat2b = feat1b;
  // RB: A1b bf16 [Mp,512] (prep out, gemm L1 in; dead after gemm L1)
  //     -> hb bf16 [Mp,512] (aggregate1 out rows [0,n); pad rows stay zeroed from A1b init).
  bf16_t* A1b = (bf16_t*)alloc((size_t)Mp * 512 * 2);  // 102.5 MB
  bf16_t* hb = A1b;
  bf16_t* W1t = (bf16_t*)alloc((size_t)512 * 512 * 2);
  bf16_t* W2t = (bf16_t*)alloc((size_t)384 * 512 * 2);
  float* el1 = (float*)alloc((size_t)n * 8 * 4);
  float* er1 = (float*)alloc((size_t)n * 8 * 4);
  float* el2 = (float*)alloc((size_t)n * 8 * 4);
  float* er2 = (float*)alloc((size_t)n * 8 * 4);
  int* deg = (int*)alloc((size_t)n * 4);
  int* cursor = (int*)alloc((size_t)n * 4);
  int* incl = (int*)alloc((size_t)n * 4);
  int* offsets = (int*)alloc((size_t)(n + 1) * 4);
  int nb = (n + 255) / 256;
  int* bsum = (int*)alloc((size_t)nb * 4);
  int* bbase = (int*)alloc((size_t)nb * 4);
  int* ssrc = (int*)alloc((size_t)e * 4);
  // total ~215 MB

  hipMemsetAsync(deg, 0, (size_t)n * 4, stream);
  hipMemsetAsync(cursor, 0, (size_t)n * 4, stream);
  // A1b/hb pad rows (read by gemm A-staging); W2t rows [336,384) (B pad; [320,336) by prep).
  hipMemsetAsync(A1b + (size_t)n * 512, 0, (size_t)(Mp - n) * 512 * 2, stream);
  hipMemsetAsync(W2t + (size_t)336 * 512, 0, (size_t)48 * 512 * 2, stream);

  int eb = (e + 255) / 256;
  count_deg<<<eb, 256, 0, stream>>>(dst, deg, e);
  scan_block<<<nb, 256, 0, stream>>>(deg, incl, bsum, n);
  scan_small<<<1, 512, 0, stream>>>(bsum, bbase, nb);
  finalize_offsets<<<nb, 256, 0, stream>>>(incl, deg, bbase, offsets, n);
  scatter_edges<<<eb, 256, 0, stream>>>(src, dst, offsets, cursor, ssrc, e);

  // ---- merged operand prep (A bf16 + W1t + W2t + Wel2/Wer2, one launch) ----
  long n8a = (long)n * 512 / 8;  // 6.4M
  long prep_total = n8a + 512 * 512 + 320 * 512 + 8 * 512;
  prep_all<<<(int)((prep_total + 255) / 256), 256, 0, stream>>>(
      features, A1b, n8a, W1, W2, al2, ar2, W1t, W2t);

  // ---- layer 1 ---- (el1/er1 fused into GEMM epilogue via wave-local reduce)
  dim3 g1(512 / 128, Mp / 128);
  gemm_bf16<0><<<g1, 256, 0, stream>>>(A1b, W1t, feat1b, al1, ar1, el1, er1, n, 512, 512);
  aggregate1<<<(n + 3) / 4, 256, 0, stream>>>(feat1b, el1, er1, offsets, ssrc, b1, hb, n);

  // ---- layer 2 ---- (feat2b overwrites feat1b — dead; el2/er2 fused via Wel2 extra cols)
  dim3 g2(384 / 128, Mp / 128);
  gemm_bf16<1><<<g2, 256, 0, stream>>>(hb, W2t, feat2b, nullptr, nullptr, el2, er2, n, 320, 512);
  aggregate2<<<(n + 3) / 4, 256, 0, stream>>>(feat2b, el2, er2, offsets, ssrc, b2, out, n);
}

// Round 17
// 470.725 us; speedup vs baseline: 1.0915x; 1.0381x over previous
//
#include <hip/hip_runtime.h>
#include <cstdint>
#include <cstddef>

#define SLOPE 0.2f
#define HEADS 8

typedef __bf16 bf16_t;
typedef __bf16 bf16x8 __attribute__((ext_vector_type(8)));
typedef float f32x4 __attribute__((ext_vector_type(4)));

// ---- merged operand prep: A fp32->bf16 (n8a vec8 elems), W1t/W2t transpose, Wel2/Wer2 ----
__global__ void prep_all(const float* __restrict__ in, bf16_t* __restrict__ outA, long n8,
                         const float* __restrict__ W1, const float* __restrict__ W2,
                         const float* __restrict__ al2, const float* __restrict__ ar2,
                         bf16_t* __restrict__ W1t, bf16_t* __restrict__ W2t) {
  long gid = (long)blockIdx.x * blockDim.x + threadIdx.x;
  if (gid < n8) {
    const float4* ip = (const float4*)in;
    float4 v0 = ip[gid * 2], v1 = ip[gid * 2 + 1];
    bf16x8 o;
    o[0] = (bf16_t)v0.x; o[1] = (bf16_t)v0.y; o[2] = (bf16_t)v0.z; o[3] = (bf16_t)v0.w;
    o[4] = (bf16_t)v1.x; o[5] = (bf16_t)v1.y; o[6] = (bf16_t)v1.z; o[7] = (bf16_t)v1.w;
    ((bf16x8*)outA)[gid] = o;
    return;
  }
  long g0 = gid - n8;
  if (g0 < 512 * 512) {
    int g = (int)g0;
    int nn = g >> 9, kk = g & 511;
    W1t[g] = (bf16_t)W1[(size_t)kk * 512 + nn];
  } else if (g0 < 512 * 512 + 320 * 512) {
    int g = (int)(g0 - 512 * 512);
    int nn = g >> 9, kk = g & 511;
    W2t[g] = (bf16_t)W2[(size_t)kk * 320 + nn];
  } else if (g0 < 512 * 512 + 320 * 512 + 8 * 512) {
    int g = (int)(g0 - (512 * 512 + 320 * 512));
    int h = g >> 9, k = g & 511;
    float a = 0.f, b = 0.f;
    for (int d = 0; d < 40; ++d) {
      float w = W2[(size_t)k * 320 + h * 40 + d];
      a = fmaf(w, al2[h * 40 + d], a);
      b = fmaf(w, ar2[h * 40 + d], b);
    }
    W2t[(size_t)(320 + h) * 512 + k] = (bf16_t)a;
    W2t[(size_t)(328 + h) * 512 + k] = (bf16_t)b;
  }
}

// ---------------- bf16 MFMA GEMM: Cb[M,NcFeat] = A[Mp,K] * Bt[Np,K]^T ----------------
// 128x128 tile, BK=64, 4 waves (2x2), global_load_lds staging, pre-swizzled-source XOR LDS
// (16B granule — conflict-free). Col tiles fastest (blockIdx.x) for A L2/L3 reuse.
// MODE 0 (layer 1): el/er computed in-epilogue from fp32 acc (wave's 64-col span == head).
// MODE 1 (layer 2): cols [NcFeat,NcFeat+8) -> elp, [NcFeat+8,NcFeat+16) -> erp (Wel2 rows).
template <int MODE>
__global__ __launch_bounds__(256) void gemm_bf16(
    const bf16_t* __restrict__ A,   // [Mp][K] bf16 (pad rows zeroed)
    const bf16_t* __restrict__ Bt,  // [Np][K] bf16 (rows beyond use zeroed)
    bf16_t* __restrict__ Cb,        // [M][NcFeat] bf16
    const float* __restrict__ al, const float* __restrict__ ar,  // MODE 0 only
    float* __restrict__ elp, float* __restrict__ erp,
    int M, int NcFeat, int K) {
  __shared__ __align__(16) unsigned char lds[32768];  // A: [0,16K), B: [16K,32K)
  const int tid = threadIdx.x;
  const int wid = tid >> 6, lane = tid & 63;
  const int wm = wid >> 1, wn = wid & 1;
  const int bm = blockIdx.y * 128, bn = blockIdx.x * 128;  // col tiles fastest
  const int quad = lane >> 4, lrow = lane & 15;

  f32x4 acc[4][4] = {};

  const int st_sub = wid * 8 + (lane >> 3);
  const int st_k = 8 * ((lane & 7) ^ (lane >> 3));
  const bf16_t* aSrc = A + (size_t)(bm + st_sub) * K + st_k;
  const bf16_t* bSrc = Bt + (size_t)(bn + st_sub) * K + st_k;

  const int xorv = (lrow & 7) << 4;
  const int aRdBase = (wm * 64 + lrow) * 128;
  const int bRdBase = (wn * 64 + lrow) * 128 + 16384;

  for (int k0 = 0; k0 < K; k0 += 64) {
    if (k0) __syncthreads();
#pragma unroll
    for (int i = 0; i < 4; ++i) {
      __builtin_amdgcn_global_load_lds(
          (const __attribute__((address_space(1))) void*)(aSrc + (size_t)i * 32 * K + k0),
          (__attribute__((address_space(3))) void*)(lds + (i * 4 + wid) * 1024), 16, 0, 0);
    }
#pragma unroll
    for (int i = 0; i < 4; ++i) {
      __builtin_amdgcn_global_load_lds(
          (const __attribute__((address_space(1))) void*)(bSrc + (size_t)i * 32 * K + k0),
          (__attribute__((address_space(3))) void*)(lds + 16384 + (i * 4 + wid) * 1024), 16, 0, 0);
    }
    __syncthreads();
#pragma unroll
    for (int kk = 0; kk < 2; ++kk) {
      bf16x8 af[4], bfr[4];
      const int kb = (kk * 64 + quad * 16) ^ xorv;
#pragma unroll
      for (int mf = 0; mf < 4; ++mf)
        af[mf] = *(const bf16x8*)(lds + aRdBase + mf * 2048 + kb);
#pragma unroll
      for (int nf = 0; nf < 4; ++nf)
        bfr[nf] = *(const bf16x8*)(lds + bRdBase + nf * 2048 + kb);
#pragma unroll
      for (int mf = 0; mf < 4; ++mf)
#pragma unroll
        for (int nf = 0; nf < 4; ++nf)
          acc[mf][nf] =
              __builtin_amdgcn_mfma_f32_16x16x32_bf16(af[mf], bfr[nf], acc[mf][nf], 0, 0, 0);
    }
  }

  // C/D layout (verified m89/m91): col = lane&15, row = (lane>>4)*4 + reg
  const int crow0 = bm + wm * 64 + quad * 4;
  const int ccol0 = bn + wn * 64 + lrow;
#pragma unroll
  for (int mf = 0; mf < 4; ++mf) {
#pragma unroll
    for (int r2 = 0; r2 < 4; ++r2) {
      int row = crow0 + mf * 16 + r2;
      if (row < M) {
#pragma unroll
        for (int nf = 0; nf < 4; ++nf) {
          int col = ccol0 + nf * 16;
          float v = acc[mf][nf][r2];
          if (col < NcFeat) {
            Cb[(size_t)row * NcFeat + col] = (bf16_t)v;
          } else if (MODE == 1) {
            if (col < NcFeat + 8) elp[(size_t)row * 8 + (col - NcFeat)] = v;
            else if (col < NcFeat + 16) erp[(size_t)row * 8 + (col - NcFeat - 8)] = v;
          }
        }
      }
    }
  }

  if (MODE == 0) {
    // this wave's 64-col span == head hh; el/er from fp32 acc, 16-lane reduce per row
    const int hh = (bn >> 6) + wn;
    float alv[4], arv[4];
#pragma unroll
    for (int nf = 0; nf < 4; ++nf) {
      alv[nf] = al[hh * 64 + lrow + nf * 16];
      arv[nf] = ar[hh * 64 + lrow + nf * 16];
    }
#pragma unroll
    for (int mf = 0; mf < 4; ++mf) {
#pragma unroll
      for (int r2 = 0; r2 < 4; ++r2) {
        float pe = 0.f, pr = 0.f;
#pragma unroll
        for (int nf = 0; nf < 4; ++nf) {
          float v = acc[mf][nf][r2];
          pe = fmaf(v, alv[nf], pe);
          pr = fmaf(v, arv[nf], pr);
        }
#pragma unroll
        for (int mask = 1; mask < 16; mask <<= 1) {
          pe += __shfl_xor(pe, mask, 64);
          pr += __shfl_xor(pr, mask, 64);
        }
        int row = crow0 + mf * 16 + r2;
        if (lrow == 0 && row < M) {
          elp[(size_t)row * 8 + hh] = pe;
          erp[(size_t)row * 8 + hh] = pr;
        }
      }
    }
  }
}

// ---------------- CSR build ----------------
__global__ void count_deg(const int* __restrict__ dst, int* __restrict__ deg, int e) {
  int gid = blockIdx.x * blockDim.x + threadIdx.x;
  if (gid < e) atomicAdd(&deg[dst[gid]], 1);
}

__global__ void scan_block(const int* __restrict__ deg, int* __restrict__ incl,
                           int* __restrict__ bsum, int n) {
  __shared__ int tmp[256];
  int t = threadIdx.x;
  int gid = blockIdx.x * 256 + t;
  int v = (gid < n) ? deg[gid] : 0;
  tmp[t] = v;
  __syncthreads();
  for (int off = 1; off < 256; off <<= 1) {
    int x = (t >= off) ? tmp[t - off] : 0;
    __syncthreads();
    tmp[t] += x;
    __syncthreads();
  }
  if (gid < n) incl[gid] = tmp[t];
  if (t == 255) bsum[blockIdx.x] = tmp[255];
}

__global__ void scan_small(const int* __restrict__ bsum, int* __restrict__ bbase, int nb) {
  __shared__ int tmp[512];
  int t = threadIdx.x;
  int v = (t < nb) ? bsum[t] : 0;
  tmp[t] = v;
  __syncthreads();
  for (int off = 1; off < 512; off <<= 1) {
    int x = (t >= off) ? tmp[t - off] : 0;
    __syncthreads();
    tmp[t] += x;
    __syncthreads();
  }
  if (t < nb) bbase[t] = tmp[t] - v;  // exclusive
}

__global__ void finalize_offsets(const int* __restrict__ incl, const int* __restrict__ deg,
                                 const int* __restrict__ bbase, int* __restrict__ offsets,
                                 int n) {
  int gid = blockIdx.x * blockDim.x + threadIdx.x;
  if (gid >= n) return;
  int base = bbase[gid >> 8];
  offsets[gid] = incl[gid] - deg[gid] + base;
  if (gid == n - 1) offsets[n] = incl[gid] + base;
}

__global__ void scatter_edges(const int* __restrict__ src, const int* __restrict__ dst,
                              const int* __restrict__ offsets, int* __restrict__ cursor,
                              int* __restrict__ ssrc, int e) {
  int gid = blockIdx.x * blockDim.x + threadIdx.x;
  if (gid < e) {
    int d = dst[gid];
    int p = offsets[d] + atomicAdd(&cursor[d], 1);
    ssrc[p] = src[gid];
  }
}

// ---------------- wave-per-node online softmax (shared by both aggregates) ----------------
__device__ inline void wave_softmax_stats(const float* __restrict__ el, float er_h, int h,
                                          int strip, const int* __restrict__ ssrc, int s0,
                                          int s1, float& m, float& ss) {
  m = -INFINITY;
  ss = 0.f;
  for (int j = s0 + strip; j < s1; j += 8) {
    int s = ssrc[j];
    float x = el[s * HEADS + h] + er_h;
    x = x > 0.f ? x : SLOPE * x;
    if (x > m) {
      ss = ss * __expf(m - x) + 1.f;
      m = x;
    } else {
      ss += __expf(x - m);
    }
  }
#pragma unroll
  for (int mask = 1; mask < 8; mask <<= 1) {
    float mo = __shfl_xor(m, mask, 64);
    float so = __shfl_xor(ss, mask, 64);
    float mn = fmaxf(m, mo);
    float e1 = (m == -INFINITY) ? 0.f : __expf(m - mn);
    float e2 = (mo == -INFINITY) ? 0.f : __expf(mo - mn);
    ss = ss * e1 + so * e2;
    m = mn;
  }
}

// ---------------- layer-1 aggregate: HD=512, D=64, bf16 gather, relu, bf16 out ----------------
// Weighted pass 4-edge unrolled (proven r16: 4 independent 16B gathers in flight).
__global__ __launch_bounds__(256) void aggregate1(
    const bf16_t* __restrict__ featb, const float* __restrict__ el,
    const float* __restrict__ er, const int* __restrict__ offsets,
    const int* __restrict__ ssrc, const float* __restrict__ bias,
    bf16_t* __restrict__ outb, int n) {
  int wid = threadIdx.x >> 6, lane = threadIdx.x & 63;
  int node = blockIdx.x * 4 + wid;
  if (node >= n) return;
  int s0 = offsets[node], s1 = offsets[node + 1];
  int h = lane >> 3, strip = lane & 7;
  float er_h = er[node * HEADS + h];
  float m, ss;
  wave_softmax_stats(el, er_h, h, strip, ssrc, s0, s1, m, ss);
  float inv_ss = 1.f / ss;

  float acc[8] = {};
  int j = s0;
  for (; j + 3 < s1; j += 4) {
    int sa = ssrc[j], sb = ssrc[j + 1], sc = ssrc[j + 2], sd = ssrc[j + 3];
    float xa = el[sa * HEADS + h] + er_h; xa = xa > 0.f ? xa : SLOPE * xa;
    float xb = el[sb * HEADS + h] + er_h; xb = xb > 0.f ? xb : SLOPE * xb;
    float xc = el[sc * HEADS + h] + er_h; xc = xc > 0.f ? xc : SLOPE * xc;
    float xd = el[sd * HEADS + h] + er_h; xd = xd > 0.f ? xd : SLOPE * xd;
    float aa = __expf(xa - m) * inv_ss;
    float ab = __expf(xb - m) * inv_ss;
    float ac = __expf(xc - m) * inv_ss;
    float ad = __expf(xd - m) * inv_ss;
    bf16x8 fa = *(const bf16x8*)(featb + (size_t)sa * 512 + lane * 8);
    bf16x8 fb = *(const bf16x8*)(featb + (size_t)sb * 512 + lane * 8);
    bf16x8 fc = *(const bf16x8*)(featb + (size_t)sc * 512 + lane * 8);
    bf16x8 fd = *(const bf16x8*)(featb + (size_t)sd * 512 + lane * 8);
#pragma unroll
    for (int i = 0; i < 8; ++i) {
      acc[i] += aa * (float)fa[i];
      acc[i] += ab * (float)fb[i];
      acc[i] += ac * (float)fc[i];
      acc[i] += ad * (float)fd[i];
    }
  }
  for (; j < s1; ++j) {
    int s = ssrc[j];
    float x = el[s * HEADS + h] + er_h;
    x = x > 0.f ? x : SLOPE * x;
    float alpha = __expf(x - m) * inv_ss;
    bf16x8 fv = *(const bf16x8*)(featb + (size_t)s * 512 + lane * 8);
#pragma unroll
    for (int i = 0; i < 8; ++i) acc[i] += alpha * (float)fv[i];
  }
  bf16x8 o;
#pragma unroll
  for (int i = 0; i < 8; ++i) {
    float v = acc[i] + bias[lane * 8 + i];
    o[i] = (bf16_t)fmaxf(v, 0.f);
  }
  *(bf16x8*)(outb + (size_t)node * 512 + lane * 8) = o;
}

// ---------------- layer-2 aggregate: HD=320, D=40, bf16 gather, fused head-mean ----------------
// Weighted pass 2-edge unrolled: 10 independent gathers in flight per iteration.
__global__ __launch_bounds__(256) void aggregate2(
    const bf16_t* __restrict__ featb, const float* __restrict__ el,
    const float* __restrict__ er, const int* __restrict__ offsets,
    const int* __restrict__ ssrc, const float* __restrict__ bias,
    float* __restrict__ out, int n) {
  __shared__ float red[4][320];
  int wid = threadIdx.x >> 6, lane = threadIdx.x & 63;
  int node = blockIdx.x * 4 + wid;
  if (node >= n) return;
  int s0 = offsets[node], s1 = offsets[node + 1];
  int h = lane >> 3, strip = lane & 7;
  float er_h = er[node * HEADS + h];
  float m, ss;
  wave_softmax_stats(el, er_h, h, strip, ssrc, s0, s1, m, ss);
  float inv_ss = 1.f / ss;

  int alane0 = ((lane + 0 * 64) / 40) * 8;
  int alane1 = ((lane + 1 * 64) / 40) * 8;
  int alane2 = ((lane + 2 * 64) / 40) * 8;
  int alane3 = ((lane + 3 * 64) / 40) * 8;
  int alane4 = ((lane + 4 * 64) / 40) * 8;

  float acc[5] = {};
  int j = s0;
  for (; j + 1 < s1; j += 2) {
    int sa = ssrc[j], sb = ssrc[j + 1];
    float xa = el[sa * HEADS + h] + er_h; xa = xa > 0.f ? xa : SLOPE * xa;
    float xb = el[sb * HEADS + h] + er_h; xb = xb > 0.f ? xb : SLOPE * xb;
    float aa = __expf(xa - m) * inv_ss;
    float ab = __expf(xb - m) * inv_ss;
    const bf16_t* fpa = featb + (size_t)sa * 320;
    const bf16_t* fpb = featb + (size_t)sb * 320;
    float a0 = __shfl(aa, alane0, 64), b0 = __shfl(ab, alane0, 64);
    float a1 = __shfl(aa, alane1, 64), b1 = __shfl(ab, alane1, 64);
    float a2 = __shfl(aa, alane2, 64), b2 = __shfl(ab, alane2, 64);
    float a3 = __shfl(aa, alane3, 64), b3 = __shfl(ab, alane3, 64);
    float a4 = __shfl(aa, alane4, 64), b4 = __shfl(ab, alane4, 64);
    float va0 = (float)fpa[lane],       vb0 = (float)fpb[lane];
    float va1 = (float)fpa[lane + 64],  vb1 = (float)fpb[lane + 64];
    float va2 = (float)fpa[lane + 128], vb2 = (float)fpb[lane + 128];
    float va3 = (float)fpa[lane + 192], vb3 = (float)fpb[lane + 192];
    float va4 = (float)fpa[lane + 256], vb4 = (float)fpb[lane + 256];
    acc[0] += a0 * va0; acc[0] += b0 * vb0;
    acc[1] += a1 * va1; acc[1] += b1 * vb1;
    acc[2] += a2 * va2; acc[2] += b2 * vb2;
    acc[3] += a3 * va3; acc[3] += b3 * vb3;
    acc[4] += a4 * va4; acc[4] += b4 * vb4;
  }
  for (; j < s1; ++j) {
    int s = ssrc[j];
    float x = el[s * HEADS + h] + er_h;
    x = x > 0.f ? x : SLOPE * x;
    float aown = __expf(x - m) * inv_ss;
    const bf16_t* fp = featb + (size_t)s * 320;
    acc[0] += __shfl(aown, alane0, 64) * (float)fp[lane];
    acc[1] += __shfl(aown, alane1, 64) * (float)fp[lane + 64];
    acc[2] += __shfl(aown, alane2, 64) * (float)fp[lane + 128];
    acc[3] += __shfl(aown, alane3, 64) * (float)fp[lane + 192];
    acc[4] += __shfl(aown, alane4, 64) * (float)fp[lane + 256];
  }
#pragma unroll
  for (int k = 0; k < 5; ++k) {
    int d = lane + k * 64;
    red[wid][d] = acc[k] + bias[d];
  }
  __builtin_amdgcn_wave_barrier();
  asm volatile("s_waitcnt lgkmcnt(0)" ::: "memory");
  __builtin_amdgcn_wave_barrier();
  if (lane < 40) {
    float s = 0.f;
#pragma unroll
    for (int hh = 0; hh < HEADS; ++hh) s += red[wid][hh * 40 + lane];
    out[(size_t)node * 40 + lane] = s * 0.125f;
  }
}

extern "C" void kernel_launch(void* const* d_in, const int* in_sizes, int n_in,
                              void* d_out, int out_size, void* d_ws, size_t ws_size,
                              hipStream_t stream) {
  const float* features = (const float*)d_in[0];
  const float* W1 = (const float*)d_in[1];
  const float* al1 = (const float*)d_in[2];
  const float* ar1 = (const float*)d_in[3];
  const float* b1 = (const float*)d_in[4];
  const float* W2 = (const float*)d_in[5];
  const float* al2 = (const float*)d_in[6];
  const float* ar2 = (const float*)d_in[7];
  const float* b2 = (const float*)d_in[8];
  const int* src = (const int*)d_in[9];
  const int* dst = (const int*)d_in[10];
  float* out = (float*)d_out;

  const int n = in_sizes[0] / 512;         // 100000
  const int e = in_sizes[9];               // 500000
  const int Mp = ((n + 127) / 128) * 128;  // 100096

  char* p = (char*)d_ws;
  auto alloc = [&](size_t bytes) {
    char* r = p;
    p += (bytes + 255) & ~(size_t)255;
    return r;
  };
  // RA: feat1b bf16 [n,512] (gemm L1 out; dead after aggregate1) -> feat2b bf16 [n,320].
  bf16_t* feat1b = (bf16_t*)alloc((size_t)n * 512 * 2);  // 102.4 MB
  bf16_t* feat2b = feat1b;
  // RB: A1b bf16 [Mp,512] (prep out, gemm L1 in; dead after gemm L1)
  //     -> hb bf16 [Mp,512] (aggregate1 out rows [0,n); pad rows stay zeroed from A1b init).
  bf16_t* A1b = (bf16_t*)alloc((size_t)Mp * 512 * 2);  // 102.5 MB
  bf16_t* hb = A1b;
  bf16_t* W1t = (bf16_t*)alloc((size_t)512 * 512 * 2);
  bf16_t* W2t = (bf16_t*)alloc((size_t)384 * 512 * 2);
  float* el1 = (float*)alloc((size_t)n * 8 * 4);
  float* er1 = (float*)alloc((size_t)n * 8 * 4);
  float* el2 = (float*)alloc((size_t)n * 8 * 4);
  float* er2 = (float*)alloc((size_t)n * 8 * 4);
  int* deg = (int*)alloc((size_t)n * 4);
  int* cursor = (int*)alloc((size_t)n * 4);
  int* incl = (int*)alloc((size_t)n * 4);
  int* offsets = (int*)alloc((size_t)(n + 1) * 4);
  int nb = (n + 255) / 256;
  int* bsum = (int*)alloc((size_t)nb * 4);
  int* bbase = (int*)alloc((size_t)nb * 4);
  int* ssrc = (int*)alloc((size_t)e * 4);
  // total ~215 MB

  // deg + cursor are adjacent 256-aligned allocations: one memset zeros both (+gap).
  size_t degpad = ((size_t)n * 4 + 255) & ~(size_t)255;
  hipMemsetAsync(deg, 0, degpad + (size_t)n * 4, stream);
  // A1b/hb pad rows (read by gemm A-staging); W2t rows [336,384) (B pad; [320,336) by prep).
  hipMemsetAsync(A1b + (size_t)n * 512, 0, (size_t)(Mp - n) * 512 * 2, stream);
  hipMemsetAsync(W2t + (size_t)336 * 512, 0, (size_t)48 * 512 * 2, stream);

  int eb = (e + 255) / 256;
  count_deg<<<eb, 256, 0, stream>>>(dst, deg, e);
  scan_block<<<nb, 256, 0, stream>>>(deg, incl, bsum, n);
  scan_small<<<1, 512, 0, stream>>>(bsum, bbase, nb);
  finalize_offsets<<<nb, 256, 0, stream>>>(incl, deg, bbase, offsets, n);
  scatter_edges<<<eb, 256, 0, stream>>>(src, dst, offsets, cursor, ssrc, e);

  // ---- merged operand prep (A bf16 + W1t + W2t + Wel2/Wer2, one launch) ----
  long n8a = (long)n * 512 / 8;  // 6.4M
  long prep_total = n8a + 512 * 512 + 320 * 512 + 8 * 512;
  prep_all<<<(int)((prep_total + 255) / 256), 256, 0, stream>>>(
      features, A1b, n8a, W1, W2, al2, ar2, W1t, W2t);

  // ---- layer 1 ---- (el1/er1 fused into GEMM epilogue via wave-local reduce)
  dim3 g1(512 / 128, Mp / 128);
  gemm_bf16<0><<<g1, 256, 0, stream>>>(A1b, W1t, feat1b, al1, ar1, el1, er1, n, 512, 512);
  aggregate1<<<(n + 3) / 4, 256, 0, stream>>>(feat1b, el1, er1, offsets, ssrc, b1, hb, n);

  // ---- layer 2 ---- (feat2b overwrites feat1b — dead; el2/er2 fused via Wel2 extra cols)
  dim3 g2(384 / 128, Mp / 128);
  gemm_bf16<1><<<g2, 256, 0, stream>>>(hb, W2t, feat2b, nullptr, nullptr, el2, er2, n, 320, 512);
  aggregate2<<<(n + 3) / 4, 256, 0, stream>>>(feat2b, el2, er2, offsets, ssrc, b2, out, n);
}